// Round 2
// baseline (345.069 us; speedup 1.0000x reference)
//
#include <hip/hip_runtime.h>

#define IMG_H 512
#define IMG_W 512
#define TILE_W 64
#define TILE_H 16
#define TILES_X (IMG_W / TILE_W)    // 8
#define TILES_Y (IMG_H / TILE_H)    // 32
#define TILES_PER_PLANE (TILES_X * TILES_Y)  // 256
#define LDSW 72   // 64 + 8 halo/alignment cols (covers x0-4 .. x0+67)
#define LDSH 22   // 16 + 6 halo rows (covers y0-3 .. y0+18)
#define NSLOTS (LDSH * (LDSW / 4))  // 396 float4 slots per tile
#define NTHREADS 256
#define TPB 12    // tiles per block -> 1024 blocks for 12288 tiles

// ---------------- compile-time coefficient generation --------------------
// (identical to the verified round-0 kernel: all coefficients evaluated at
// compile time in double precision; they become inline literals.)

constexpr double PI_D = 3.141592653589793238462643383279502884;

constexpr double cexp(double x) {
  double term = 1.0, sum = 1.0;
  for (int n = 1; n < 48; ++n) { term *= x / n; sum += term; }
  return sum;
}
constexpr double ccos(double x) {
  double term = 1.0, sum = 1.0;
  for (int n = 1; n < 24; ++n) {
    term *= -x * x / ((2.0 * n - 1.0) * (2.0 * n));
    sum += term;
  }
  return sum;
}
constexpr double csin(double x) {
  double term = x, sum = x;
  for (int n = 1; n < 24; ++n) {
    term *= -x * x / ((2.0 * n) * (2.0 * n + 1.0));
    sum += term;
  }
  return sum;
}
constexpr double cabs_(double x) { return x < 0 ? -x : x; }

struct KTabs {
  float lpf[9];
  float log3[9];
  float log5[25];
  float log7[49];
  float hpf3[9];
  float hpf5[25];
  float gab[4][49];
};

constexpr void fill_log(int ks, double sigma, float* out) {
  double buf[49] = {};
  double s = 0.0;
  const int h = ks / 2;
  for (int i = 0; i < ks; ++i) {
    for (int j = 0; j < ks; ++j) {
      const double xi = (double)(i - h);
      const double yj = (double)(j - h);
      const double r2 = xi * xi + yj * yj;
      const double g = cexp(-r2 / (2.0 * sigma * sigma));
      const double lap = -1.0 / (PI_D * sigma * sigma * sigma * sigma) *
                         (1.0 - r2 / (2.0 * sigma * sigma));
      buf[i * ks + j] = lap * g;
      s += cabs_(lap * g);
    }
  }
  for (int k = 0; k < ks * ks; ++k) out[k] = (float)(buf[k] / s);
}

constexpr void fill_gabor(double ang_deg, float* out) {
  const double th = ang_deg * PI_D / 180.0;
  const double ct = ccos(th), st = csin(th);
  double buf[49] = {};
  double s = 0.0;
  for (int i = 0; i < 7; ++i) {
    for (int j = 0; j < 7; ++j) {
      const double xv = (double)(j - 3);
      const double yv = (double)(i - 3);
      const double xt = xv * ct + yv * st;
      const double yt = -xv * st + yv * ct;
      const double g = cexp(-(xt * xt / 4.0 + yt * yt / 4.0) / 2.0) *
                       ccos(2.0 * PI_D * 0.1 * xt);
      buf[i * 7 + j] = g;
      s += cabs_(g);
    }
  }
  for (int k = 0; k < 49; ++k) out[k] = (float)(buf[k] / s);
}

constexpr KTabs make_tabs() {
  KTabs t{};
  const double lv[9] = {1, 2, 1, 2, 4, 2, 1, 2, 1};
  for (int k = 0; k < 9; ++k) t.lpf[k] = (float)(lv[k] / 16.0);
  for (int k = 0; k < 9; ++k) t.hpf3[k] = -1.0f;
  t.hpf3[4] = 8.0f;
  for (int k = 0; k < 25; ++k) t.hpf5[k] = -1.0f;
  t.hpf5[12] = 24.0f;
  fill_log(3, 0.8, t.log3);
  fill_log(5, 1.0, t.log5);
  fill_log(7, 1.4, t.log7);
  fill_gabor(0.0, t.gab[0]);
  fill_gabor(45.0, t.gab[1]);
  fill_gabor(90.0, t.gab[2]);
  fill_gabor(135.0, t.gab[3]);
  return t;
}

constexpr KTabs KT = make_tabs();

// ------------------------------- helpers ---------------------------------

typedef float f4v __attribute__((ext_vector_type(4)));

__device__ __forceinline__ float fast_tanh(float x) {
  float e = __builtin_amdgcn_exp2f(x * 2.8853900817779268f);
  return 1.0f - 2.0f * __builtin_amdgcn_rcpf(e + 1.0f);
}
__device__ __forceinline__ float squash_from(float z) {
  return fmaf(fast_tanh(0.1f * z), 0.5f, 0.5f);
}

__device__ __forceinline__ void store_nt(float* p, float a, float b, float c,
                                         float d) {
  f4v v = {a, b, c, d};
  __builtin_nontemporal_store(v, (f4v*)p);
}

__device__ __forceinline__ float4 guarded_load(const float* __restrict__ in,
                                               int gy, int gx) {
  float4 v = make_float4(0.f, 0.f, 0.f, 0.f);
  if ((unsigned)gy < IMG_H) {
    const float* rowp = in + (size_t)gy * IMG_W;
    if (gx >= 0 && gx + 3 < IMG_W) {
      v = *(const float4*)(rowp + gx);
    } else {
      if ((unsigned)(gx + 0) < IMG_W) v.x = rowp[gx + 0];
      if ((unsigned)(gx + 1) < IMG_W) v.y = rowp[gx + 1];
      if ((unsigned)(gx + 2) < IMG_W) v.z = rowp[gx + 2];
      if ((unsigned)(gx + 3) < IMG_W) v.w = rowp[gx + 3];
    }
  }
  return v;
}

__device__ __forceinline__ void tile_decode(int t, int& x0, int& y0, int& pl) {
  pl = t >> 8;                 // 256 tiles per plane
  const int rem = t & 255;
  y0 = (rem >> 3) * TILE_H;    // 8 tiles across
  x0 = (rem & 7) * TILE_W;
}

// ------------------------------- kernel ----------------------------------
// Inter-tile software pipeline: each block processes TPB tiles; while tile t
// is computed from LDS buffer `cur`, tile t+1's global loads are already in
// flight into registers (issue-early / write-late), landing in buffer cur^1
// behind a single barrier per tile. Removes the stage->barrier->compute
// convoy that capped VALUBusy at ~40%.

__global__ __launch_bounds__(NTHREADS)
void msif_kernel(const float* __restrict__ x, float* __restrict__ out,
                 int planes, int do_gab, int tiles_total) {
  __shared__ float lds[2][LDSH * LDSW];   // 2 x 6336 B = 12672 B

  const int tid = threadIdx.x;
  const int tx = tid & 15;   // 16 threads wide, 4 px each -> 64 cols
  const int ty = tid >> 4;   // 16 rows, 1 px each
  // per-thread staging slots (fixed): slot A = tid, slot B = tid + 256
  const int rA = tid / (LDSW / 4);
  const int cA = (tid % (LDSW / 4)) * 4;
  const int slotB = tid + NTHREADS;
  const bool hasB = slotB < NSLOTS;
  const int rB = slotB / (LDSW / 4);
  const int cB = (slotB % (LDSW / 4)) * 4;

  const int t0 = blockIdx.x * TPB;
  if (t0 >= tiles_total) return;

  const size_t fs = (size_t)planes * (IMG_H * IMG_W);

  // ---- prologue: stage tile t0 into buffer 0 ----
  {
    int x0, y0, pl;
    tile_decode(t0, x0, y0, pl);
    const float* in = x + (size_t)pl * (IMG_H * IMG_W);
    const float4 va = guarded_load(in, y0 - 3 + rA, x0 - 4 + cA);
    float4 vb = make_float4(0.f, 0.f, 0.f, 0.f);
    if (hasB) vb = guarded_load(in, y0 - 3 + rB, x0 - 4 + cB);
    *(float4*)&lds[0][rA * LDSW + cA] = va;
    if (hasB) *(float4*)&lds[0][rB * LDSW + cB] = vb;
  }
  __syncthreads();

  int cur = 0;
  for (int i = 0; i < TPB; ++i) {
    const int t = t0 + i;
    if (t >= tiles_total) break;            // uniform across block
    int x0, y0, pl;
    tile_decode(t, x0, y0, pl);
    const bool havenext = (i + 1 < TPB) && (t + 1 < tiles_total);

    // ---- issue next tile's loads NOW (latency hides under compute) ----
    float4 va = make_float4(0.f, 0.f, 0.f, 0.f);
    float4 vb = make_float4(0.f, 0.f, 0.f, 0.f);
    if (havenext) {
      int nx0, ny0, npl;
      tile_decode(t + 1, nx0, ny0, npl);
      const float* nin = x + (size_t)npl * (IMG_H * IMG_W);
      va = guarded_load(nin, ny0 - 3 + rA, nx0 - 4 + cA);
      if (hasB) vb = guarded_load(nin, ny0 - 3 + rB, nx0 - 4 + cB);
    }

    // ---- compute tile t from lds[cur] (verbatim round-0 core) ----
    const float* __restrict__ tl = lds[cur];

    float l7[4] = {}, l5[4] = {}, l3[4] = {};
    float h5[4] = {}, h3[4] = {}, lp[4] = {};
    float g0[4] = {}, g1[4] = {}, g2[4] = {}, g3[4] = {};

#pragma unroll
    for (int ir = 0; ir < 7; ++ir) {
      const float4* p = (const float4*)&tl[(ty + ir) * LDSW + 4 * tx];
      float4 w0 = p[0], w1 = p[1], w2 = p[2];
      float w[12] = {w0.x, w0.y, w0.z, w0.w, w1.x, w1.y, w1.z, w1.w,
                     w2.x, w2.y, w2.z, w2.w};

#pragma unroll
      for (int dx = 0; dx < 7; ++dx) {
        const float c7 = KT.log7[ir * 7 + dx];
        const float cg0 = KT.gab[0][ir * 7 + dx];
        const float cg1 = KT.gab[1][ir * 7 + dx];
        const float cg2 = KT.gab[2][ir * 7 + dx];
        const float cg3 = KT.gab[3][ir * 7 + dx];
#pragma unroll
        for (int c = 0; c < 4; ++c) {
          const float v = w[c + dx + 1];
          l7[c] = fmaf(v, c7, l7[c]);
          g0[c] = fmaf(v, cg0, g0[c]);
          g1[c] = fmaf(v, cg1, g1[c]);
          g2[c] = fmaf(v, cg2, g2[c]);
          g3[c] = fmaf(v, cg3, g3[c]);
        }
      }
      if (ir >= 1 && ir <= 5) {
        const int kr = ir - 1;
#pragma unroll
        for (int dx = 0; dx < 5; ++dx) {
          const float c5 = KT.log5[kr * 5 + dx];
          const float ch5 = KT.hpf5[kr * 5 + dx];
#pragma unroll
          for (int c = 0; c < 4; ++c) {
            const float v = w[c + dx + 2];
            l5[c] = fmaf(v, c5, l5[c]);
            h5[c] = fmaf(v, ch5, h5[c]);
          }
        }
      }
      if (ir >= 2 && ir <= 4) {
        const int kr = ir - 2;
#pragma unroll
        for (int dx = 0; dx < 3; ++dx) {
          const float cl = KT.lpf[kr * 3 + dx];
          const float c3 = KT.log3[kr * 3 + dx];
          const float ch3 = KT.hpf3[kr * 3 + dx];
#pragma unroll
          for (int c = 0; c < 4; ++c) {
            const float v = w[c + dx + 3];
            lp[c] = fmaf(v, cl, lp[c]);
            l3[c] = fmaf(v, c3, l3[c]);
            h3[c] = fmaf(v, ch3, h3[c]);
          }
        }
      }
    }

    // ---- epilogue: max commutes with monotone tanh/squash; nt stores ----
    const int X = x0 + 4 * tx;
    const int yo = y0 + ty;
    const size_t off = (size_t)pl * (IMG_H * IMG_W) + (size_t)yo * IMG_W + X;

    const float4 orig = *(const float4*)&tl[(ty + 3) * LDSW + 4 * tx + 4];
    store_nt(out + off, orig.x, orig.y, orig.z, orig.w);

    float lo[4], ho[4], go[4];
#pragma unroll
    for (int c = 0; c < 4; ++c) {
      lo[c] = squash_from(fmaxf(fmaxf(l3[c], l5[c]), l7[c]));
      ho[c] = squash_from(fmaxf(h3[c], h5[c]));
      go[c] = fast_tanh(0.1f * fmaxf(fmaxf(g0[c], g1[c]), fmaxf(g2[c], g3[c])));
    }
    store_nt(out + fs + off, lp[0], lp[1], lp[2], lp[3]);
    store_nt(out + 2 * fs + off, lo[0], lo[1], lo[2], lo[3]);
    store_nt(out + 3 * fs + off, ho[0], ho[1], ho[2], ho[3]);
    if (do_gab) store_nt(out + 4 * fs + off, go[0], go[1], go[2], go[3]);

    // ---- land next tile into the other buffer; one barrier per tile ----
    if (havenext) {
      *(float4*)&lds[cur ^ 1][rA * LDSW + cA] = va;
      if (hasB) *(float4*)&lds[cur ^ 1][rB * LDSW + cB] = vb;
      __syncthreads();
      cur ^= 1;
    }
  }
}

extern "C" void kernel_launch(void* const* d_in, const int* in_sizes, int n_in,
                              void* d_out, int out_size, void* d_ws, size_t ws_size,
                              hipStream_t stream) {
  const float* x = (const float*)d_in[0];
  float* out = (float*)d_out;
  const int plane_elems = IMG_H * IMG_W;
  const int planes = in_sizes[0] / plane_elems;               // 16*3 = 48
  const int do_gab = (out_size >= 5 * in_sizes[0]) ? 1 : 0;
  const int tiles_total = planes * TILES_PER_PLANE;           // 12288
  const int nblocks = (tiles_total + TPB - 1) / TPB;          // 1024

  msif_kernel<<<dim3(nblocks), NTHREADS, 0, stream>>>(x, out, planes, do_gab,
                                                      tiles_total);
}

// Round 5
// 334.019 us; speedup vs baseline: 1.0331x; 1.0331x over previous
//
#include <hip/hip_runtime.h>

#define IMG_H 512
#define IMG_W 512
#define TILE_H 16
#define BANDS (IMG_H / TILE_H)   // 32
#define LDSW 520   // 4 zero cols | 512 | 4 zero cols
#define LDSH 22    // 3 halo | 16 | 3 halo
#define ROWSLOTS (LDSW / 4)      // 130 float4 slots per row
#define NTHREADS 256

// ---------------- compile-time coefficient generation --------------------
// (identical to the verified round-0 kernel)

constexpr double PI_D = 3.141592653589793238462643383279502884;

constexpr double cexp(double x) {
  double term = 1.0, sum = 1.0;
  for (int n = 1; n < 48; ++n) { term *= x / n; sum += term; }
  return sum;
}
constexpr double ccos(double x) {
  double term = 1.0, sum = 1.0;
  for (int n = 1; n < 24; ++n) {
    term *= -x * x / ((2.0 * n - 1.0) * (2.0 * n));
    sum += term;
  }
  return sum;
}
constexpr double csin(double x) {
  double term = x, sum = x;
  for (int n = 1; n < 24; ++n) {
    term *= -x * x / ((2.0 * n) * (2.0 * n + 1.0));
    sum += term;
  }
  return sum;
}
constexpr double cabs_(double x) { return x < 0 ? -x : x; }

struct KTabs {
  float lpf[9];
  float log3[9];
  float log5[25];
  float log7[49];
  float hpf3[9];
  float hpf5[25];
  float gab[4][49];
};

constexpr void fill_log(int ks, double sigma, float* out) {
  double buf[49] = {};
  double s = 0.0;
  const int h = ks / 2;
  for (int i = 0; i < ks; ++i) {
    for (int j = 0; j < ks; ++j) {
      const double xi = (double)(i - h);
      const double yj = (double)(j - h);
      const double r2 = xi * xi + yj * yj;
      const double g = cexp(-r2 / (2.0 * sigma * sigma));
      const double lap = -1.0 / (PI_D * sigma * sigma * sigma * sigma) *
                         (1.0 - r2 / (2.0 * sigma * sigma));
      buf[i * ks + j] = lap * g;
      s += cabs_(lap * g);
    }
  }
  for (int k = 0; k < ks * ks; ++k) out[k] = (float)(buf[k] / s);
}

constexpr void fill_gabor(double ang_deg, float* out) {
  const double th = ang_deg * PI_D / 180.0;
  const double ct = ccos(th), st = csin(th);
  double buf[49] = {};
  double s = 0.0;
  for (int i = 0; i < 7; ++i) {
    for (int j = 0; j < 7; ++j) {
      const double xv = (double)(j - 3);
      const double yv = (double)(i - 3);
      const double xt = xv * ct + yv * st;
      const double yt = -xv * st + yv * ct;
      const double g = cexp(-(xt * xt / 4.0 + yt * yt / 4.0) / 2.0) *
                       ccos(2.0 * PI_D * 0.1 * xt);
      buf[i * 7 + j] = g;
      s += cabs_(g);
    }
  }
  for (int k = 0; k < 49; ++k) out[k] = (float)(buf[k] / s);
}

constexpr KTabs make_tabs() {
  KTabs t{};
  const double lv[9] = {1, 2, 1, 2, 4, 2, 1, 2, 1};
  for (int k = 0; k < 9; ++k) t.lpf[k] = (float)(lv[k] / 16.0);
  for (int k = 0; k < 9; ++k) t.hpf3[k] = -1.0f;
  t.hpf3[4] = 8.0f;
  for (int k = 0; k < 25; ++k) t.hpf5[k] = -1.0f;
  t.hpf5[12] = 24.0f;
  fill_log(3, 0.8, t.log3);
  fill_log(5, 1.0, t.log5);
  fill_log(7, 1.4, t.log7);
  fill_gabor(0.0, t.gab[0]);
  fill_gabor(45.0, t.gab[1]);
  fill_gabor(90.0, t.gab[2]);
  fill_gabor(135.0, t.gab[3]);
  return t;
}

constexpr KTabs KT = make_tabs();

// ------------------------------- helpers ---------------------------------

__device__ __forceinline__ float fast_tanh(float x) {
  float e = __builtin_amdgcn_exp2f(x * 2.8853900817779268f);
  return 1.0f - 2.0f * __builtin_amdgcn_rcpf(e + 1.0f);
}
__device__ __forceinline__ float squash_from(float z) {
  return fmaf(fast_tanh(0.1f * z), 0.5f, 0.5f);
}

// ------------------------------- kernel ----------------------------------
// Full-width row-band tiles. Each block: 512x16 output band of one plane.
// Each wave owns whole rows -> every global store instruction covers a
// CONTIGUOUS 1 KB (64 lanes x 16 B); each block writes 32 KB contiguous per
// output stream. This replaces the 256 B-granular scattered writes of the
// 64x16-tile versions (the invariant across R0-R2's flat ~160 us).

__global__ __launch_bounds__(NTHREADS)
void msif_kernel(const float* __restrict__ x, float* __restrict__ out,
                 int planes, int do_gab) {
  __shared__ float tile[LDSH * LDSW];   // 45,760 B -> 3 blocks/CU

  const int tid = threadIdx.x;
  const int lane = tid & 63;
  const int wv = tid >> 6;             // 4 waves, each owns rows wv+4*it
  const int b = blockIdx.x;
  const int pl = b >> 5;               // 32 bands per plane
  const int band = b & 31;
  const int y0 = band * TILE_H;
  const float* __restrict__ in = x + (size_t)pl * (IMG_H * IMG_W);

  // ---- stage 22 rows x 520 cols (zero side/vertical padding) ----
  const int gy0 = y0 - 3;
  for (int sl = tid; sl < LDSH * ROWSLOTS; sl += NTHREADS) {
    const int r = sl / ROWSLOTS;
    const int c = sl - r * ROWSLOTS;         // 0..129
    const int gy = gy0 + r;
    float4 v = make_float4(0.f, 0.f, 0.f, 0.f);
    if ((unsigned)gy < IMG_H && (unsigned)(c - 1) < 128u)
      v = *(const float4*)(in + (size_t)gy * IMG_W + (size_t)(c - 1) * 4);
    *(float4*)&tile[r * LDSW + 4 * c] = v;
  }
  __syncthreads();

  const size_t fs = (size_t)planes * (IMG_H * IMG_W);

#pragma unroll 1
  for (int it = 0; it < 4; ++it) {
    const int yl = wv + 4 * it;              // local output row 0..15
#pragma unroll 1
    for (int s = 0; s < 2; ++s) {
      const int colbase = 256 * s + 4 * lane;  // output col of px 0

      float l7[4] = {}, l5[4] = {}, l3[4] = {};
      float h5[4] = {}, h3[4] = {}, lp[4] = {};
      float g0[4] = {}, g1[4] = {}, g2[4] = {}, g3[4] = {};
      float4 orig = make_float4(0.f, 0.f, 0.f, 0.f);

#pragma unroll
      for (int ir = 0; ir < 7; ++ir) {
        const float4* p =
            (const float4*)&tile[(yl + ir) * LDSW + colbase];  // col-4 origin
        float4 w0 = p[0], w1 = p[1], w2 = p[2];
        float w[12] = {w0.x, w0.y, w0.z, w0.w, w1.x, w1.y, w1.z, w1.w,
                       w2.x, w2.y, w2.z, w2.w};
        if (ir == 3) orig = make_float4(w[4], w[5], w[6], w[7]);

#pragma unroll
        for (int dx = 0; dx < 7; ++dx) {
          const float c7 = KT.log7[ir * 7 + dx];
          const float cg0 = KT.gab[0][ir * 7 + dx];
          const float cg1 = KT.gab[1][ir * 7 + dx];
          const float cg2 = KT.gab[2][ir * 7 + dx];
          const float cg3 = KT.gab[3][ir * 7 + dx];
#pragma unroll
          for (int c = 0; c < 4; ++c) {
            const float v = w[c + dx + 1];
            l7[c] = fmaf(v, c7, l7[c]);
            g0[c] = fmaf(v, cg0, g0[c]);
            g1[c] = fmaf(v, cg1, g1[c]);
            g2[c] = fmaf(v, cg2, g2[c]);
            g3[c] = fmaf(v, cg3, g3[c]);
          }
        }
        if (ir >= 1 && ir <= 5) {
          const int kr = ir - 1;
#pragma unroll
          for (int dx = 0; dx < 5; ++dx) {
            const float c5 = KT.log5[kr * 5 + dx];
            const float ch5 = KT.hpf5[kr * 5 + dx];
#pragma unroll
            for (int c = 0; c < 4; ++c) {
              const float v = w[c + dx + 2];
              l5[c] = fmaf(v, c5, l5[c]);
              h5[c] = fmaf(v, ch5, h5[c]);
            }
          }
        }
        if (ir >= 2 && ir <= 4) {
          const int kr = ir - 2;
#pragma unroll
          for (int dx = 0; dx < 3; ++dx) {
            const float cl = KT.lpf[kr * 3 + dx];
            const float c3 = KT.log3[kr * 3 + dx];
            const float ch3 = KT.hpf3[kr * 3 + dx];
#pragma unroll
            for (int c = 0; c < 4; ++c) {
              const float v = w[c + dx + 3];
              lp[c] = fmaf(v, cl, lp[c]);
              l3[c] = fmaf(v, c3, l3[c]);
              h3[c] = fmaf(v, ch3, h3[c]);
            }
          }
        }
      }

      // ---- epilogue: max commutes with monotone tanh/squash; store ----
      const int yo = y0 + yl;
      const size_t off =
          (size_t)pl * (IMG_H * IMG_W) + (size_t)yo * IMG_W + colbase;

      *(float4*)(out + off) = orig;

      float lo[4], ho[4], go[4];
#pragma unroll
      for (int c = 0; c < 4; ++c) {
        lo[c] = squash_from(fmaxf(fmaxf(l3[c], l5[c]), l7[c]));
        ho[c] = squash_from(fmaxf(h3[c], h5[c]));
        go[c] =
            fast_tanh(0.1f * fmaxf(fmaxf(g0[c], g1[c]), fmaxf(g2[c], g3[c])));
      }
      *(float4*)(out + fs + off) = make_float4(lp[0], lp[1], lp[2], lp[3]);
      *(float4*)(out + 2 * fs + off) = make_float4(lo[0], lo[1], lo[2], lo[3]);
      *(float4*)(out + 3 * fs + off) = make_float4(ho[0], ho[1], ho[2], ho[3]);
      if (do_gab)
        *(float4*)(out + 4 * fs + off) = make_float4(go[0], go[1], go[2], go[3]);
    }
  }
}

extern "C" void kernel_launch(void* const* d_in, const int* in_sizes, int n_in,
                              void* d_out, int out_size, void* d_ws, size_t ws_size,
                              hipStream_t stream) {
  const float* x = (const float*)d_in[0];
  float* out = (float*)d_out;
  const int plane_elems = IMG_H * IMG_W;
  const int planes = in_sizes[0] / plane_elems;               // 16*3 = 48
  const int do_gab = (out_size >= 5 * in_sizes[0]) ? 1 : 0;

  msif_kernel<<<dim3(planes * BANDS), NTHREADS, 0, stream>>>(x, out, planes,
                                                             do_gab);
}